// Round 7
// baseline (193.716 us; speedup 1.0000x reference)
//
#include <hip/hip_runtime.h>
#include <hip/hip_bf16.h>
#include <hip/hip_fp16.h>
#include <stdint.h>

typedef _Float16 half8 __attribute__((ext_vector_type(8)));
typedef _Float16 half4_t __attribute__((ext_vector_type(4)));
typedef __fp16 fp16x2 __attribute__((ext_vector_type(2)));
typedef float f32x4 __attribute__((ext_vector_type(4)));

// async global->LDS, 16B per lane. LDS dst must be wave-uniform base + lane*16.
__device__ __forceinline__ void lds_load16(const _Float16* g, _Float16* l) {
    __builtin_amdgcn_global_load_lds(
        (const __attribute__((address_space(1))) void*)g,
        (__attribute__((address_space(3))) void*)l, 16, 0, 0);
}

// ---------------------------------------------------------------------------
// fp32 -> fp16 conversions: nodes (8192x512), Wcat = [Wq;Wk;Wv], Wo
// ---------------------------------------------------------------------------
__global__ __launch_bounds__(256) void prep_convert(
    const float* __restrict__ nodes, const float* __restrict__ wq,
    const float* __restrict__ wk, const float* __restrict__ wv,
    const float* __restrict__ wo,
    _Float16* __restrict__ x16, _Float16* __restrict__ wcat,
    _Float16* __restrict__ wo16)
{
    const int t = blockIdx.x * 256 + threadIdx.x;   // 0 .. 1048575
    {
        const float4 v = ((const float4*)nodes)[t];
        half4_t o;
        o[0] = (_Float16)v.x; o[1] = (_Float16)v.y;
        o[2] = (_Float16)v.z; o[3] = (_Float16)v.w;
        *(half4_t*)(x16 + (size_t)t * 4) = o;
    }
    if (t < 65536) {
        float4 v; half4_t o;
        v = ((const float4*)wq)[t];
        o[0]=(_Float16)v.x; o[1]=(_Float16)v.y; o[2]=(_Float16)v.z; o[3]=(_Float16)v.w;
        *(half4_t*)(wcat + (size_t)t * 4) = o;
        v = ((const float4*)wk)[t];
        o[0]=(_Float16)v.x; o[1]=(_Float16)v.y; o[2]=(_Float16)v.z; o[3]=(_Float16)v.w;
        *(half4_t*)(wcat + 262144 + (size_t)t * 4) = o;
        v = ((const float4*)wv)[t];
        o[0]=(_Float16)v.x; o[1]=(_Float16)v.y; o[2]=(_Float16)v.z; o[3]=(_Float16)v.w;
        *(half4_t*)(wcat + 524288 + (size_t)t * 4) = o;
        v = ((const float4*)wo)[t];
        o[0]=(_Float16)v.x; o[1]=(_Float16)v.y; o[2]=(_Float16)v.z; o[3]=(_Float16)v.w;
        *(half4_t*)(wo16 + (size_t)t * 4) = o;
    }
}

// ---------------------------------------------------------------------------
// QKV projection: X[8192,512] @ Wcat[1536,512]^T -> scatter q/k/v [bh][i][d]
// q is pre-scaled by (1/sqrt(64)) * log2(e) here, so attention can use
// exp2 directly (v_exp_f32 computes 2^x).
// ---------------------------------------------------------------------------
__global__ __launch_bounds__(256, 3) void gemm_qkv(
    const _Float16* __restrict__ X, const _Float16* __restrict__ Wcat,
    const float* __restrict__ bq, const float* __restrict__ bk,
    const float* __restrict__ bv,
    _Float16* __restrict__ q16, _Float16* __restrict__ k16,
    _Float16* __restrict__ v16)
{
    __shared__ _Float16 As[128 * 32];
    __shared__ _Float16 Bs[128 * 32];
    const int t = threadIdx.x;
    const int bm = blockIdx.x, bn = blockIdx.y;
    const int wave = t >> 6, lane = t & 63;
    const int wm = (wave >> 1) * 64, wn = (wave & 1) * 64;
    const int quad = lane >> 4, l16 = lane & 15;

    f32x4 acc[4][4];
#pragma unroll
    for (int a = 0; a < 4; a++)
#pragma unroll
        for (int b2 = 0; b2 < 4; b2++) acc[a][b2] = (f32x4){0.f, 0.f, 0.f, 0.f};

    const _Float16* Ab = X + (size_t)bm * 128 * 512;
    const _Float16* Bb = Wcat + (size_t)bn * 128 * 512;
    const int srow = t >> 2, scol = (t & 3) * 8;

    for (int k0 = 0; k0 < 512; k0 += 32) {
        __syncthreads();
        lds_load16(Ab + (size_t)srow * 512 + k0 + scol, As + t * 8);
        lds_load16(Ab + (size_t)(srow + 64) * 512 + k0 + scol, As + 2048 + t * 8);
        lds_load16(Bb + (size_t)srow * 512 + k0 + scol, Bs + t * 8);
        lds_load16(Bb + (size_t)(srow + 64) * 512 + k0 + scol, Bs + 2048 + t * 8);
        __syncthreads();
        half8 af[4], bf[4];
#pragma unroll
        for (int mi = 0; mi < 4; mi++)
            af[mi] = *(const half8*)&As[(wm + mi * 16 + l16) * 32 + quad * 8];
#pragma unroll
        for (int ni = 0; ni < 4; ni++)
            bf[ni] = *(const half8*)&Bs[(wn + ni * 16 + l16) * 32 + quad * 8];
#pragma unroll
        for (int mi = 0; mi < 4; mi++)
#pragma unroll
            for (int ni = 0; ni < 4; ni++)
                acc[mi][ni] = __builtin_amdgcn_mfma_f32_16x16x32_f16(
                    af[mi], bf[ni], acc[mi][ni], 0, 0, 0);
    }

    const int sel = bn >> 2;
    const float* bias = sel == 0 ? bq : (sel == 1 ? bk : bv);
    _Float16* outp = sel == 0 ? q16 : (sel == 1 ? k16 : v16);
    // q: fold 1/sqrt(D) * log2(e) so softmax runs in exp2 domain
    const float scale = sel == 0 ? 0.18033688011112042f : 1.0f;
    const int colbase = (bn & 3) * 128 + wn + l16;
#pragma unroll
    for (int mi = 0; mi < 4; mi++) {
#pragma unroll
        for (int r = 0; r < 4; r++) {
            const int m = bm * 128 + wm + mi * 16 + quad * 4 + r;
            const int ii = m >> 3, bb = m & 7;
#pragma unroll
            for (int ni = 0; ni < 4; ni++) {
                const int f = colbase + ni * 16;
                const int hh = f >> 6, dd = f & 63;
                const float val = (acc[mi][ni][r] + bias[f]) * scale;
                outp[(size_t)((bb * 8 + hh) * 1024 + ii) * 64 + dd] = (_Float16)val;
            }
        }
    }
}

// ---------------------------------------------------------------------------
// Flash-style MFMA attention v7 = v5 (verified) + two diagnosed fixes:
//   - edge bias DOUBLE-buffered again (v5 single-buffered it -> exposed
//     ~300-500cy L2 wait before softmax every jt; v3->v5 regression).
//   - Vts stride 72 -> 68: stride 72 made lanes l16/l16+8 alias (delta
//     1152B = 0 mod 128B) -> structural 2-way on every PV b64 read
//     (= the entire 2.10M conflict count: 524,288 reads x 4 cyc).
//     With 68, PV reads / V commit / kf reads all sit at the bank floor.
//   - everything else identical to v5: 256 threads, 4 waves x 32 q-rows,
//     swapped QK^T (s = mfma(K,Q)), P in-register as 16x16x16 A-frags via
//     cvt_pkrtz, rowsum via ones-MFMA, K via global_load_lds with
//     XOR-chunk swizzle, ONE barrier per jt.
// ---------------------------------------------------------------------------
__global__ __launch_bounds__(256) void attn_fused(
    const _Float16* __restrict__ q16, const _Float16* __restrict__ k16,
    const _Float16* __restrict__ v16, const float* __restrict__ edges,
    const float* __restrict__ rel_bias, _Float16* __restrict__ attn16)
{
    __shared__ _Float16 Ks[2][64 * 64];    // 2 x 8,192 B, swizzled linear
    __shared__ _Float16 Vts[2][64 * 68];   // 2 x 8,704 B, V^T stride 68

    const int t = threadIdx.x;
    const int bh = blockIdx.x;
    const int b = bh >> 3, h = bh & 7;
    const int i0 = blockIdx.y << 7;
    const int wave = t >> 6, lane = t & 63;
    const int quad = lane >> 4, l16 = lane & 15;
    const float rb = rel_bias[h] * 1.4426950408889634f;   // log2(e)

    const _Float16* Qb = q16 + (size_t)bh * 65536;
    const _Float16* Kb = k16 + (size_t)bh * 65536;
    const _Float16* Vb = v16 + (size_t)bh * 65536;

    // ---- Q rows for this wave, in registers, loaded once ----
    half8 aq[2][2];
#pragma unroll
    for (int mt = 0; mt < 2; mt++) {
        const _Float16* qp =
            Qb + (size_t)(i0 + wave * 32 + mt * 16 + l16) * 64 + quad * 8;
        aq[mt][0] = *(const half8*)(qp);
        aq[mt][1] = *(const half8*)(qp + 32);
    }

    f32x4 acc_o[2][4], acc_l[2];
#pragma unroll
    for (int mt = 0; mt < 2; mt++) {
        acc_l[mt] = (f32x4){0.f, 0.f, 0.f, 0.f};
#pragma unroll
        for (int nd = 0; nd < 4; nd++) acc_o[mt][nd] = (f32x4){0.f, 0.f, 0.f, 0.f};
    }

    const half4_t ones4 = {(_Float16)1.f, (_Float16)1.f, (_Float16)1.f, (_Float16)1.f};

    // V staging: thread owns V[srow][scol..scol+15] of the 64x64 tile
    const int srow = t >> 2, scol = (t & 3) * 16;
    const int vswb = srow ^ (((scol >> 4) & 3) << 4);
    const int jrd_x = (l16 & 3) << 3;
    const int jrd_base = 4 * quad;

    // K DMA: thread t stages 16B to Ks+t*8(elems) from pre-swizzled source
    const int kj = t >> 3;
    const int kc = ((t & 7) ^ (kj & 7)) << 3;
    const _Float16* kdma = Kb + (size_t)kj * 64 + kc;

    half8 vp0, vp1;
    float4 ebA[2][4], ebB[2][4];

    // ---- prologue: edges(0), K(0) DMA, V(0) commit, vp <- V(1) ----
#pragma unroll
    for (int mt = 0; mt < 2; mt++)
#pragma unroll
        for (int nt = 0; nt < 4; nt++)
            ebA[mt][nt] = *(const float4*)&edges[
                (size_t)(i0 + wave * 32 + mt * 16 + l16) * 1024 + nt * 16 + quad * 4];
    lds_load16(kdma, &Ks[0][t * 8]);
    lds_load16(kdma + 32 * 64, &Ks[0][2048 + t * 8]);
    vp0 = *(const half8*)(Vb + (size_t)srow * 64 + scol);
    vp1 = *(const half8*)(Vb + (size_t)srow * 64 + scol + 8);
#pragma unroll
    for (int e = 0; e < 8; e++) {
        Vts[0][(scol + e) * 68 + (vswb ^ ((e & 3) << 3))]     = vp0[e];
        Vts[0][(scol + 8 + e) * 68 + (vswb ^ ((e & 3) << 3))] = vp1[e];
    }
    vp0 = *(const half8*)(Vb + (size_t)(64 + srow) * 64 + scol);
    vp1 = *(const half8*)(Vb + (size_t)(64 + srow) * 64 + scol + 8);
    __syncthreads();

#define STEP(JT, CBUF, EC, EN)                                                 \
    {                                                                          \
        if ((JT) + 64 < 1024) {                                                \
            _Pragma("unroll")                                                  \
            for (int mt_ = 0; mt_ < 2; mt_++)                                  \
                _Pragma("unroll")                                              \
                for (int nt_ = 0; nt_ < 4; nt_++)                              \
                    EN[mt_][nt_] = *(const float4*)&edges[                     \
                        (size_t)(i0 + wave * 32 + mt_ * 16 + l16) * 1024 +     \
                        (JT) + 64 + nt_ * 16 + quad * 4];                      \
            lds_load16(kdma + (size_t)((JT) + 64) * 64,                        \
                       &Ks[CBUF ^ 1][t * 8]);                                  \
            lds_load16(kdma + (size_t)((JT) + 96) * 64,                        \
                       &Ks[CBUF ^ 1][2048 + t * 8]);                           \
        }                                                                      \
        half8 kf[4][2];                                                        \
        _Pragma("unroll")                                                      \
        for (int nt_ = 0; nt_ < 4; nt_++)                                      \
            _Pragma("unroll")                                                  \
            for (int kk_ = 0; kk_ < 2; kk_++)                                  \
                kf[nt_][kk_] = *(const half8*)&Ks[CBUF][                       \
                    (nt_ * 16 + l16) * 64 +                                    \
                    (((kk_ * 4 + quad) ^ (l16 & 7)) << 3)];                    \
        f32x4 s_[2][4];                                                        \
        _Pragma("unroll")                                                      \
        for (int mt_ = 0; mt_ < 2; mt_++)                                      \
            _Pragma("unroll")                                                  \
            for (int nt_ = 0; nt_ < 4; nt_++)                                  \
                s_[mt_][nt_] = (f32x4){-8.f, -8.f, -8.f, -8.f};                \
        __builtin_amdgcn_s_setprio(1);                                         \
        _Pragma("unroll")                                                      \
        for (int kk_ = 0; kk_ < 2; kk_++)                                      \
            _Pragma("unroll")                                                  \
            for (int mt_ = 0; mt_ < 2; mt_++)                                  \
                _Pragma("unroll")                                              \
                for (int nt_ = 0; nt_ < 4; nt_++)                              \
                    s_[mt_][nt_] = __builtin_amdgcn_mfma_f32_16x16x32_f16(     \
                        kf[nt_][kk_], aq[mt_][kk_], s_[mt_][nt_], 0, 0, 0);    \
        __builtin_amdgcn_s_setprio(0);                                         \
        half4_t pa_[2][4];                                                     \
        _Pragma("unroll")                                                      \
        for (int mt_ = 0; mt_ < 2; mt_++)                                      \
            _Pragma("unroll")                                                  \
            for (int nt_ = 0; nt_ < 4; nt_++) {                                \
                const float p0_ = __builtin_amdgcn_exp2f(                      \
                    fmaf(EC[mt_][nt_].x, rb, s_[mt_][nt_][0]));                \
                const float p1_ = __builtin_amdgcn_exp2f(                      \
                    fmaf(EC[mt_][nt_].y, rb, s_[mt_][nt_][1]));                \
                const float p2_ = __builtin_amdgcn_exp2f(                      \
                    fmaf(EC[mt_][nt_].z, rb, s_[mt_][nt_][2]));                \
                const float p3_ = __builtin_amdgcn_exp2f(                      \
                    fmaf(EC[mt_][nt_].w, rb, s_[mt_][nt_][3]));                \
                const fp16x2 lo_ = __builtin_amdgcn_cvt_pkrtz(p0_, p1_);       \
                const fp16x2 hi_ = __builtin_amdgcn_cvt_pkrtz(p2_, p3_);       \
                half4_t pk_;                                                   \
                pk_[0] = (_Float16)lo_[0]; pk_[1] = (_Float16)lo_[1];          \
                pk_[2] = (_Float16)hi_[0]; pk_[3] = (_Float16)hi_[1];          \
                pa_[mt_][nt_] = pk_;                                           \
            }                                                                  \
        if ((JT) + 64 < 1024) {                                                \
            _Pragma("unroll")                                                  \
            for (int e_ = 0; e_ < 8; e_++) {                                   \
                Vts[CBUF ^ 1][(scol + e_) * 68 + (vswb ^ ((e_ & 3) << 3))]     \
                    = vp0[e_];                                                 \
                Vts[CBUF ^ 1][(scol + 8 + e_) * 68 + (vswb ^ ((e_ & 3) << 3))] \
                    = vp1[e_];                                                 \
            }                                                                  \
            if ((JT) + 128 < 1024) {                                           \
                vp0 = *(const half8*)(Vb + (size_t)((JT) + 128 + srow) * 64 + scol);     \
                vp1 = *(const half8*)(Vb + (size_t)((JT) + 128 + srow) * 64 + scol + 8); \
            }                                                                  \
        }                                                                      \
        __builtin_amdgcn_s_setprio(1);                                         \
        _Pragma("unroll")                                                      \
        for (int nt_ = 0; nt_ < 4; nt_++) {                                    \
            acc_l[0] = __builtin_amdgcn_mfma_f32_16x16x16f16(                  \
                pa_[0][nt_], ones4, acc_l[0], 0, 0, 0);                        \
            acc_l[1] = __builtin_amdgcn_mfma_f32_16x16x16f16(                  \
                pa_[1][nt_], ones4, acc_l[1], 0, 0, 0);                        \
            _Pragma("unroll")                                                  \
            for (int nd_ = 0; nd_ < 4; nd_++) {                                \
                const half4_t vb_ = *(const half4_t*)&Vts[CBUF][               \
                    (nd_ * 16 + l16) * 68 +                                    \
                    (((nt_ * 16 + jrd_base) ^ jrd_x) ^ (nd_ << 4))];           \
                acc_o[0][nd_] = __builtin_amdgcn_mfma_f32_16x16x16f16(         \
                    pa_[0][nt_], vb_, acc_o[0][nd_], 0, 0, 0);                 \
                acc_o[1][nd_] = __builtin_amdgcn_mfma_f32_16x16x16f16(         \
                    pa_[1][nt_], vb_, acc_o[1][nd_], 0, 0, 0);                 \
            }                                                                  \
        }                                                                      \
        __builtin_amdgcn_s_setprio(0);                                         \
        __syncthreads();                                                       \
    }

    for (int jt = 0; jt < 1024; jt += 128) {
        STEP(jt, 0, ebA, ebB);
        STEP(jt + 64, 1, ebB, ebA);
    }
#undef STEP

    // ---- finalize: acc_l holds row sums in the same C-layout as acc_o ----
#pragma unroll
    for (int mt = 0; mt < 2; mt++) {
#pragma unroll
        for (int r = 0; r < 4; r++) {
            const float inv = 1.0f / acc_l[mt][r];
            const int i = i0 + wave * 32 + mt * 16 + quad * 4 + r;
            _Float16* orow = attn16 + ((size_t)i * 8 + b) * 512 + h * 64;
#pragma unroll
            for (int nd = 0; nd < 4; nd++)
                orow[nd * 16 + l16] = (_Float16)(acc_o[mt][nd][r] * inv);
        }
    }
}

// ---------------------------------------------------------------------------
// Output projection: attn16[8192,512] @ Wo[512,512]^T + bo -> d_out fp32
// 64x128 tiles -> grid (128,4) = 512 blocks = 2 blocks/CU.
// ---------------------------------------------------------------------------
__global__ __launch_bounds__(256, 4) void gemm_out(
    const _Float16* __restrict__ A, const _Float16* __restrict__ W,
    const float* __restrict__ bo, float* __restrict__ dout)
{
    __shared__ _Float16 As[64 * 32];
    __shared__ _Float16 Bs[128 * 32];
    const int t = threadIdx.x;
    const int bm = blockIdx.x, bn = blockIdx.y;
    const int wave = t >> 6, lane = t & 63;
    const int wm = (wave >> 1) * 32, wn = (wave & 1) * 64;
    const int quad = lane >> 4, l16 = lane & 15;

    f32x4 acc[2][4];
#pragma unroll
    for (int a = 0; a < 2; a++)
#pragma unroll
        for (int b2 = 0; b2 < 4; b2++) acc[a][b2] = (f32x4){0.f, 0.f, 0.f, 0.f};

    const _Float16* Ab = A + (size_t)bm * 64 * 512;
    const _Float16* Bb = W + (size_t)bn * 128 * 512;
    const int srow = t >> 2, scol = (t & 3) * 8;

    for (int k0 = 0; k0 < 512; k0 += 32) {
        __syncthreads();
        lds_load16(Ab + (size_t)srow * 512 + k0 + scol, As + t * 8);
        lds_load16(Bb + (size_t)srow * 512 + k0 + scol, Bs + t * 8);
        lds_load16(Bb + (size_t)(srow + 64) * 512 + k0 + scol, Bs + 2048 + t * 8);
        __syncthreads();
        half8 af[2], bf[4];
#pragma unroll
        for (int mi = 0; mi < 2; mi++)
            af[mi] = *(const half8*)&As[(wm + mi * 16 + l16) * 32 + quad * 8];
#pragma unroll
        for (int ni = 0; ni < 4; ni++)
            bf[ni] = *(const half8*)&Bs[(wn + ni * 16 + l16) * 32 + quad * 8];
#pragma unroll
        for (int mi = 0; mi < 2; mi++)
#pragma unroll
            for (int ni = 0; ni < 4; ni++)
                acc[mi][ni] = __builtin_amdgcn_mfma_f32_16x16x32_f16(
                    af[mi], bf[ni], acc[mi][ni], 0, 0, 0);
    }
#pragma unroll
    for (int mi = 0; mi < 2; mi++) {
#pragma unroll
        for (int r = 0; r < 4; r++) {
            const int m = bm * 64 + wm + mi * 16 + quad * 4 + r;
#pragma unroll
            for (int ni = 0; ni < 4; ni++) {
                const int n = bn * 128 + wn + ni * 16 + l16;
                dout[(size_t)m * 512 + n] = acc[mi][ni][r] + bo[n];
            }
        }
    }
}

// ---------------------------------------------------------------------------
extern "C" void kernel_launch(void* const* d_in, const int* in_sizes, int n_in,
                              void* d_out, int out_size, void* d_ws, size_t ws_size,
                              hipStream_t stream)
{
    (void)in_sizes; (void)n_in; (void)out_size; (void)ws_size;
    const float* nodes    = (const float*)d_in[0];
    const float* edges    = (const float*)d_in[1];
    const float* Wq       = (const float*)d_in[2];
    const float* bq       = (const float*)d_in[3];
    const float* Wk       = (const float*)d_in[4];
    const float* bk       = (const float*)d_in[5];
    const float* Wv       = (const float*)d_in[6];
    const float* bv       = (const float*)d_in[7];
    const float* rel_bias = (const float*)d_in[8];
    const float* Wo       = (const float*)d_in[9];
    const float* bo       = (const float*)d_in[10];
    float* out = (float*)d_out;

    char* ws = (char*)d_ws;
    _Float16* x16    = (_Float16*)(ws);              //  8,388,608 B
    _Float16* wcat   = (_Float16*)(ws +  8388608);   //  1,572,864 B
    _Float16* wo16   = (_Float16*)(ws +  9961472);   //    524,288 B
    _Float16* q16    = (_Float16*)(ws + 10485760);   //  8,388,608 B
    _Float16* k16    = (_Float16*)(ws + 18874368);   //  8,388,608 B
    _Float16* v16    = (_Float16*)(ws + 27262976);   //  8,388,608 B
    _Float16* attn16 = (_Float16*)(ws + 35651584);   //  8,388,608 B

    hipLaunchKernelGGL(prep_convert, dim3(4096), dim3(256), 0, stream,
                       nodes, Wq, Wk, Wv, Wo, x16, wcat, wo16);
    hipLaunchKernelGGL(gemm_qkv, dim3(64, 12), dim3(256), 0, stream,
                       x16, wcat, bq, bk, bv, q16, k16, v16);
    hipLaunchKernelGGL(attn_fused, dim3(64, 8), dim3(256), 0, stream,
                       q16, k16, v16, edges, rel_bias, attn16);
    hipLaunchKernelGGL(gemm_out, dim3(128, 4), dim3(256), 0, stream,
                       attn16, wo16, bo, out);
}

// Round 8
// 157.311 us; speedup vs baseline: 1.2314x; 1.2314x over previous
//
#include <hip/hip_runtime.h>
#include <hip/hip_bf16.h>
#include <hip/hip_fp16.h>
#include <stdint.h>

typedef _Float16 half8 __attribute__((ext_vector_type(8)));
typedef _Float16 half4_t __attribute__((ext_vector_type(4)));
typedef __fp16 fp16x2 __attribute__((ext_vector_type(2)));
typedef float f32x4 __attribute__((ext_vector_type(4)));

// async global->LDS, 16B per lane. LDS dst must be wave-uniform base + lane*16.
__device__ __forceinline__ void lds_load16(const _Float16* g, _Float16* l) {
    __builtin_amdgcn_global_load_lds(
        (const __attribute__((address_space(1))) void*)g,
        (__attribute__((address_space(3))) void*)l, 16, 0, 0);
}

// ---------------------------------------------------------------------------
// fp32 -> fp16 conversions: nodes (8192x512), Wcat = [Wq;Wk;Wv], Wo
// ---------------------------------------------------------------------------
__global__ __launch_bounds__(256) void prep_convert(
    const float* __restrict__ nodes, const float* __restrict__ wq,
    const float* __restrict__ wk, const float* __restrict__ wv,
    const float* __restrict__ wo,
    _Float16* __restrict__ x16, _Float16* __restrict__ wcat,
    _Float16* __restrict__ wo16)
{
    const int t = blockIdx.x * 256 + threadIdx.x;   // 0 .. 1048575
    {
        const float4 v = ((const float4*)nodes)[t];
        half4_t o;
        o[0] = (_Float16)v.x; o[1] = (_Float16)v.y;
        o[2] = (_Float16)v.z; o[3] = (_Float16)v.w;
        *(half4_t*)(x16 + (size_t)t * 4) = o;
    }
    if (t < 65536) {
        float4 v; half4_t o;
        v = ((const float4*)wq)[t];
        o[0]=(_Float16)v.x; o[1]=(_Float16)v.y; o[2]=(_Float16)v.z; o[3]=(_Float16)v.w;
        *(half4_t*)(wcat + (size_t)t * 4) = o;
        v = ((const float4*)wk)[t];
        o[0]=(_Float16)v.x; o[1]=(_Float16)v.y; o[2]=(_Float16)v.z; o[3]=(_Float16)v.w;
        *(half4_t*)(wcat + 262144 + (size_t)t * 4) = o;
        v = ((const float4*)wv)[t];
        o[0]=(_Float16)v.x; o[1]=(_Float16)v.y; o[2]=(_Float16)v.z; o[3]=(_Float16)v.w;
        *(half4_t*)(wcat + 524288 + (size_t)t * 4) = o;
        v = ((const float4*)wo)[t];
        o[0]=(_Float16)v.x; o[1]=(_Float16)v.y; o[2]=(_Float16)v.z; o[3]=(_Float16)v.w;
        *(half4_t*)(wo16 + (size_t)t * 4) = o;
    }
}

// ---------------------------------------------------------------------------
// QKV projection: X[8192,512] @ Wcat[1536,512]^T -> scatter q/k/v [bh][i][d]
// q is pre-scaled by (1/sqrt(64)) * log2(e) here, so attention can use
// exp2 directly (v_exp_f32 computes 2^x).
// ---------------------------------------------------------------------------
__global__ __launch_bounds__(256, 3) void gemm_qkv(
    const _Float16* __restrict__ X, const _Float16* __restrict__ Wcat,
    const float* __restrict__ bq, const float* __restrict__ bk,
    const float* __restrict__ bv,
    _Float16* __restrict__ q16, _Float16* __restrict__ k16,
    _Float16* __restrict__ v16)
{
    __shared__ _Float16 As[128 * 32];
    __shared__ _Float16 Bs[128 * 32];
    const int t = threadIdx.x;
    const int bm = blockIdx.x, bn = blockIdx.y;
    const int wave = t >> 6, lane = t & 63;
    const int wm = (wave >> 1) * 64, wn = (wave & 1) * 64;
    const int quad = lane >> 4, l16 = lane & 15;

    f32x4 acc[4][4];
#pragma unroll
    for (int a = 0; a < 4; a++)
#pragma unroll
        for (int b2 = 0; b2 < 4; b2++) acc[a][b2] = (f32x4){0.f, 0.f, 0.f, 0.f};

    const _Float16* Ab = X + (size_t)bm * 128 * 512;
    const _Float16* Bb = Wcat + (size_t)bn * 128 * 512;
    const int srow = t >> 2, scol = (t & 3) * 8;

    for (int k0 = 0; k0 < 512; k0 += 32) {
        __syncthreads();
        lds_load16(Ab + (size_t)srow * 512 + k0 + scol, As + t * 8);
        lds_load16(Ab + (size_t)(srow + 64) * 512 + k0 + scol, As + 2048 + t * 8);
        lds_load16(Bb + (size_t)srow * 512 + k0 + scol, Bs + t * 8);
        lds_load16(Bb + (size_t)(srow + 64) * 512 + k0 + scol, Bs + 2048 + t * 8);
        __syncthreads();
        half8 af[4], bf[4];
#pragma unroll
        for (int mi = 0; mi < 4; mi++)
            af[mi] = *(const half8*)&As[(wm + mi * 16 + l16) * 32 + quad * 8];
#pragma unroll
        for (int ni = 0; ni < 4; ni++)
            bf[ni] = *(const half8*)&Bs[(wn + ni * 16 + l16) * 32 + quad * 8];
#pragma unroll
        for (int mi = 0; mi < 4; mi++)
#pragma unroll
            for (int ni = 0; ni < 4; ni++)
                acc[mi][ni] = __builtin_amdgcn_mfma_f32_16x16x32_f16(
                    af[mi], bf[ni], acc[mi][ni], 0, 0, 0);
    }

    const int sel = bn >> 2;
    const float* bias = sel == 0 ? bq : (sel == 1 ? bk : bv);
    _Float16* outp = sel == 0 ? q16 : (sel == 1 ? k16 : v16);
    // q: fold 1/sqrt(D) * log2(e) so softmax runs in exp2 domain
    const float scale = sel == 0 ? 0.18033688011112042f : 1.0f;
    const int colbase = (bn & 3) * 128 + wn + l16;
#pragma unroll
    for (int mi = 0; mi < 4; mi++) {
#pragma unroll
        for (int r = 0; r < 4; r++) {
            const int m = bm * 128 + wm + mi * 16 + quad * 4 + r;
            const int ii = m >> 3, bb = m & 7;
#pragma unroll
            for (int ni = 0; ni < 4; ni++) {
                const int f = colbase + ni * 16;
                const int hh = f >> 6, dd = f & 63;
                const float val = (acc[mi][ni][r] + bias[f]) * scale;
                outp[(size_t)((bb * 8 + hh) * 1024 + ii) * 64 + dd] = (_Float16)val;
            }
        }
    }
}

// ---------------------------------------------------------------------------
// Flash-style MFMA attention v8 = v5 (48us, verified) with a pair-pipeline:
//   - 4-buffer K/V rotation, ONE barrier per TWO j-tiles (9 barriers vs 17).
//     Pair P computes bufs {2P&3,(2P+1)&3} while DMA/commit fill {+2,+3};
//     reads and writes are disjoint buffer sets, the pair-end barrier
//     separates them. Step 2k+1's QK overlaps step 2k's PV (no barrier
//     between).
//   - kf-interleave in QK: 2 frags live instead of 8 (-24 VGPR in the
//     fattest phase) to fund the 2nd vp set; target VGPR <= 128 (hard
//     occupancy cliff measured at >128: v7 140 VGPR -> occupancy halved).
//   - edges SINGLE-buffered at step top (v5 pattern; prefetch-across-
//     barrier measured-harmful in v7).
//   - Vts stride 68 + swizzle (validated: PV-read conflicts halved).
//   - everything else v5-verified: swapped QK^T, in-reg P via cvt_pkrtz,
//     ones-MFMA rowsum, K-DMA with XOR-chunk pre-swizzle.
// ---------------------------------------------------------------------------
__global__ __launch_bounds__(256) void attn_fused(
    const _Float16* __restrict__ q16, const _Float16* __restrict__ k16,
    const _Float16* __restrict__ v16, const float* __restrict__ edges,
    const float* __restrict__ rel_bias, _Float16* __restrict__ attn16)
{
    __shared__ _Float16 Ks4[4 * 4096];     // 32,768 B, swizzled linear
    __shared__ _Float16 Vts4[4 * 4352];    // 34,816 B, V^T stride 68

    const int t = threadIdx.x;
    const int bh = blockIdx.x;
    const int b = bh >> 3, h = bh & 7;
    const int i0 = blockIdx.y << 7;
    const int wave = t >> 6, lane = t & 63;
    const int quad = lane >> 4, l16 = lane & 15;
    const float rb = rel_bias[h] * 1.4426950408889634f;   // log2(e)

    const _Float16* Qb = q16 + (size_t)bh * 65536;
    const _Float16* Kb = k16 + (size_t)bh * 65536;
    const _Float16* Vb = v16 + (size_t)bh * 65536;

    // ---- Q rows for this wave, in registers, loaded once ----
    half8 aq[2][2];
#pragma unroll
    for (int mt = 0; mt < 2; mt++) {
        const _Float16* qp =
            Qb + (size_t)(i0 + wave * 32 + mt * 16 + l16) * 64 + quad * 8;
        aq[mt][0] = *(const half8*)(qp);
        aq[mt][1] = *(const half8*)(qp + 32);
    }

    f32x4 acc_o[2][4], acc_l[2];
#pragma unroll
    for (int mt = 0; mt < 2; mt++) {
        acc_l[mt] = (f32x4){0.f, 0.f, 0.f, 0.f};
#pragma unroll
        for (int nd = 0; nd < 4; nd++) acc_o[mt][nd] = (f32x4){0.f, 0.f, 0.f, 0.f};
    }

    const half4_t ones4 = {(_Float16)1.f, (_Float16)1.f, (_Float16)1.f, (_Float16)1.f};

    // V staging: thread owns V[srow][scol..scol+15] of the 64x64 tile
    const int srow = t >> 2, scol = (t & 3) * 16;
    const int vswb = srow ^ (((scol >> 4) & 3) << 4);
    const int jrd_x = (l16 & 3) << 3;
    const int jrd_base = 4 * quad;

    // K DMA: thread t stages 16B from pre-swizzled global source
    const int kj = t >> 3;
    const int kc = ((t & 7) ^ (kj & 7)) << 3;
    const _Float16* kdma = Kb + (size_t)kj * 64 + kc;

    half8 vpA0, vpA1, vpB0, vpB1;

#define LOADV(V0, V1, TILE)                                                    \
    {                                                                          \
        const _Float16* vp_ = Vb + (size_t)((TILE) * 64 + srow) * 64 + scol;   \
        V0 = *(const half8*)(vp_);                                             \
        V1 = *(const half8*)(vp_ + 8);                                         \
    }
#define COMMITV(SB, V0, V1)                                                    \
    {                                                                          \
        _Float16* vb_ = Vts4 + (SB) * 4352;                                    \
        _Pragma("unroll")                                                      \
        for (int e_ = 0; e_ < 8; e_++) {                                       \
            vb_[(scol + e_) * 68 + (vswb ^ ((e_ & 3) << 3))]     = V0[e_];     \
            vb_[(scol + 8 + e_) * 68 + (vswb ^ ((e_ & 3) << 3))] = V1[e_];     \
        }                                                                      \
    }
#define DMAK(SB, TILE)                                                         \
    {                                                                          \
        lds_load16(kdma + (size_t)(TILE) * 4096,                               \
                   Ks4 + (SB) * 4096 + t * 8);                                 \
        lds_load16(kdma + (size_t)(TILE) * 4096 + 2048,                        \
                   Ks4 + (SB) * 4096 + 2048 + t * 8);                          \
    }

    // ---- prologue: K(0),K(1) DMA; V(0),V(1) commit; vpA<-V(2), vpB<-V(3) ----
    DMAK(0, 0);
    DMAK(1, 1);
    LOADV(vpA0, vpA1, 0);
    COMMITV(0, vpA0, vpA1);
    LOADV(vpA0, vpA1, 1);
    COMMITV(1, vpA0, vpA1);
    LOADV(vpA0, vpA1, 2);
    LOADV(vpB0, vpB1, 3);
    __syncthreads();

#define STEP(S, V0, V1, DOBAR)                                                 \
    {                                                                          \
        const _Float16* ksb_ = Ks4 + ((S) & 3) * 4096;                         \
        const _Float16* vtb_ = Vts4 + ((S) & 3) * 4352;                        \
        float4 ec[2][4];                                                       \
        _Pragma("unroll")                                                      \
        for (int mt_ = 0; mt_ < 2; mt_++)                                      \
            _Pragma("unroll")                                                  \
            for (int nt_ = 0; nt_ < 4; nt_++)                                  \
                ec[mt_][nt_] = *(const float4*)&edges[                         \
                    (size_t)(i0 + wave * 32 + mt_ * 16 + l16) * 1024 +         \
                    (S) * 64 + nt_ * 16 + quad * 4];                           \
        if ((S) + 2 < 16) DMAK(((S) + 2) & 3, (S) + 2);                        \
        f32x4 s_[2][4];                                                        \
        _Pragma("unroll")                                                      \
        for (int mt_ = 0; mt_ < 2; mt_++)                                      \
            _Pragma("unroll")                                                  \
            for (int nt_ = 0; nt_ < 4; nt_++)                                  \
                s_[mt_][nt_] = (f32x4){-8.f, -8.f, -8.f, -8.f};                \
        __builtin_amdgcn_s_setprio(1);                                         \
        _Pragma("unroll")                                                      \
        for (int nt_ = 0; nt_ < 4; nt_++) {                                    \
            const half8 kf0_ = *(const half8*)&ksb_[                           \
                (nt_ * 16 + l16) * 64 + ((quad ^ (l16 & 7)) << 3)];            \
            const half8 kf1_ = *(const half8*)&ksb_[                           \
                (nt_ * 16 + l16) * 64 + (((4 + quad) ^ (l16 & 7)) << 3)];      \
            s_[0][nt_] = __builtin_amdgcn_mfma_f32_16x16x32_f16(               \
                kf0_, aq[0][0], s_[0][nt_], 0, 0, 0);                          \
            s_[1][nt_] = __builtin_amdgcn_mfma_f32_16x16x32_f16(               \
                kf0_, aq[1][0], s_[1][nt_], 0, 0, 0);                          \
            s_[0][nt_] = __builtin_amdgcn_mfma_f32_16x16x32_f16(               \
                kf1_, aq[0][1], s_[0][nt_], 0, 0, 0);                          \
            s_[1][nt_] = __builtin_amdgcn_mfma_f32_16x16x32_f16(               \
                kf1_, aq[1][1], s_[1][nt_], 0, 0, 0);                          \
        }                                                                      \
        __builtin_amdgcn_s_setprio(0);                                         \
        half4_t pa_[2][4];                                                     \
        _Pragma("unroll")                                                      \
        for (int mt_ = 0; mt_ < 2; mt_++)                                      \
            _Pragma("unroll")                                                  \
            for (int nt_ = 0; nt_ < 4; nt_++) {                                \
                const float p0_ = __builtin_amdgcn_exp2f(                      \
                    fmaf(ec[mt_][nt_].x, rb, s_[mt_][nt_][0]));                \
                const float p1_ = __builtin_amdgcn_exp2f(                      \
                    fmaf(ec[mt_][nt_].y, rb, s_[mt_][nt_][1]));                \
                const float p2_ = __builtin_amdgcn_exp2f(                      \
                    fmaf(ec[mt_][nt_].z, rb, s_[mt_][nt_][2]));                \
                const float p3_ = __builtin_amdgcn_exp2f(                      \
                    fmaf(ec[mt_][nt_].w, rb, s_[mt_][nt_][3]));                \
                const fp16x2 lo_ = __builtin_amdgcn_cvt_pkrtz(p0_, p1_);       \
                const fp16x2 hi_ = __builtin_amdgcn_cvt_pkrtz(p2_, p3_);       \
                half4_t pk_;                                                   \
                pk_[0] = (_Float16)lo_[0]; pk_[1] = (_Float16)lo_[1];          \
                pk_[2] = (_Float16)hi_[0]; pk_[3] = (_Float16)hi_[1];          \
                pa_[mt_][nt_] = pk_;                                           \
            }                                                                  \
        if ((S) + 2 < 16) COMMITV(((S) + 2) & 3, V0, V1);                      \
        if ((S) + 4 < 16) LOADV(V0, V1, (S) + 4);                              \
        __builtin_amdgcn_s_setprio(1);                                         \
        _Pragma("unroll")                                                      \
        for (int nt_ = 0; nt_ < 4; nt_++) {                                    \
            acc_l[0] = __builtin_amdgcn_mfma_f32_16x16x16f16(                  \
                pa_[0][nt_], ones4, acc_l[0], 0, 0, 0);                        \
            acc_l[1] = __builtin_amdgcn_mfma_f32_16x16x16f16(                  \
                pa_[1][nt_], ones4, acc_l[1], 0, 0, 0);                        \
            _Pragma("unroll")                                                  \
            for (int nd_ = 0; nd_ < 4; nd_++) {                                \
                const half4_t vb_ = *(const half4_t*)&vtb_[                    \
                    (nd_ * 16 + l16) * 68 +                                    \
                    (((nt_ * 16 + jrd_base) ^ jrd_x) ^ (nd_ << 4))];           \
                acc_o[0][nd_] = __builtin_amdgcn_mfma_f32_16x16x16f16(         \
                    pa_[0][nt_], vb_, acc_o[0][nd_], 0, 0, 0);                 \
                acc_o[1][nd_] = __builtin_amdgcn_mfma_f32_16x16x16f16(         \
                    pa_[1][nt_], vb_, acc_o[1][nd_], 0, 0, 0);                 \
            }                                                                  \
        }                                                                      \
        __builtin_amdgcn_s_setprio(0);                                         \
        if (DOBAR) __syncthreads();                                            \
    }

#pragma unroll
    for (int p = 0; p < 8; p++) {
        STEP(2 * p,     vpA0, vpA1, 0);
        STEP(2 * p + 1, vpB0, vpB1, 1);
    }
#undef STEP
#undef DMAK
#undef COMMITV
#undef LOADV

    // ---- finalize: acc_l holds row sums in the same C-layout as acc_o ----
#pragma unroll
    for (int mt = 0; mt < 2; mt++) {
#pragma unroll
        for (int r = 0; r < 4; r++) {
            const float inv = 1.0f / acc_l[mt][r];
            const int i = i0 + wave * 32 + mt * 16 + quad * 4 + r;
            _Float16* orow = attn16 + ((size_t)i * 8 + b) * 512 + h * 64;
#pragma unroll
            for (int nd = 0; nd < 4; nd++)
                orow[nd * 16 + l16] = (_Float16)(acc_o[mt][nd][r] * inv);
        }
    }
}

// ---------------------------------------------------------------------------
// Output projection: attn16[8192,512] @ Wo[512,512]^T + bo -> d_out fp32
// 64x128 tiles -> grid (128,4) = 512 blocks = 2 blocks/CU.
// ---------------------------------------------------------------------------
__global__ __launch_bounds__(256, 4) void gemm_out(
    const _Float16* __restrict__ A, const _Float16* __restrict__ W,
    const float* __restrict__ bo, float* __restrict__ dout)
{
    __shared__ _Float16 As[64 * 32];
    __shared__ _Float16 Bs[128 * 32];
    const int t = threadIdx.x;
    const int bm = blockIdx.x, bn = blockIdx.y;
    const int wave = t >> 6, lane = t & 63;
    const int wm = (wave >> 1) * 32, wn = (wave & 1) * 64;
    const int quad = lane >> 4, l16 = lane & 15;

    f32x4 acc[2][4];
#pragma unroll
    for (int a = 0; a < 2; a++)
#pragma unroll
        for (int b2 = 0; b2 < 4; b2++) acc[a][b2] = (f32x4){0.f, 0.f, 0.f, 0.f};

    const _Float16* Ab = A + (size_t)bm * 64 * 512;
    const _Float16* Bb = W + (size_t)bn * 128 * 512;
    const int srow = t >> 2, scol = (t & 3) * 8;

    for (int k0 = 0; k0 < 512; k0 += 32) {
        __syncthreads();
        lds_load16(Ab + (size_t)srow * 512 + k0 + scol, As + t * 8);
        lds_load16(Bb + (size_t)srow * 512 + k0 + scol, Bs + t * 8);
        lds_load16(Bb + (size_t)(srow + 64) * 512 + k0 + scol, Bs + 2048 + t * 8);
        __syncthreads();
        half8 af[2], bf[4];
#pragma unroll
        for (int mi = 0; mi < 2; mi++)
            af[mi] = *(const half8*)&As[(wm + mi * 16 + l16) * 32 + quad * 8];
#pragma unroll
        for (int ni = 0; ni < 4; ni++)
            bf[ni] = *(const half8*)&Bs[(wn + ni * 16 + l16) * 32 + quad * 8];
#pragma unroll
        for (int mi = 0; mi < 2; mi++)
#pragma unroll
            for (int ni = 0; ni < 4; ni++)
                acc[mi][ni] = __builtin_amdgcn_mfma_f32_16x16x32_f16(
                    af[mi], bf[ni], acc[mi][ni], 0, 0, 0);
    }
#pragma unroll
    for (int mi = 0; mi < 2; mi++) {
#pragma unroll
        for (int r = 0; r < 4; r++) {
            const int m = bm * 64 + wm + mi * 16 + quad * 4 + r;
#pragma unroll
            for (int ni = 0; ni < 4; ni++) {
                const int n = bn * 128 + wn + ni * 16 + l16;
                dout[(size_t)m * 512 + n] = acc[mi][ni][r] + bo[n];
            }
        }
    }
}

// ---------------------------------------------------------------------------
extern "C" void kernel_launch(void* const* d_in, const int* in_sizes, int n_in,
                              void* d_out, int out_size, void* d_ws, size_t ws_size,
                              hipStream_t stream)
{
    (void)in_sizes; (void)n_in; (void)out_size; (void)ws_size;
    const float* nodes    = (const float*)d_in[0];
    const float* edges    = (const float*)d_in[1];
    const float* Wq       = (const float*)d_in[2];
    const float* bq       = (const float*)d_in[3];
    const float* Wk       = (const float*)d_in[4];
    const float* bk       = (const float*)d_in[5];
    const float* Wv       = (const float*)d_in[6];
    const float* bv       = (const float*)d_in[7];
    const float* rel_bias = (const float*)d_in[8];
    const float* Wo       = (const float*)d_in[9];
    const float* bo       = (const float*)d_in[10];
    float* out = (float*)d_out;

    char* ws = (char*)d_ws;
    _Float16* x16    = (_Float16*)(ws);              //  8,388,608 B
    _Float16* wcat   = (_Float16*)(ws +  8388608);   //  1,572,864 B
    _Float16* wo16   = (_Float16*)(ws +  9961472);   //    524,288 B
    _Float16* q16    = (_Float16*)(ws + 10485760);   //  8,388,608 B
    _Float16* k16    = (_Float16*)(ws + 18874368);   //  8,388,608 B
    _Float16* v16    = (_Float16*)(ws + 27262976);   //  8,388,608 B
    _Float16* attn16 = (_Float16*)(ws + 35651584);   //  8,388,608 B

    hipLaunchKernelGGL(prep_convert, dim3(4096), dim3(256), 0, stream,
                       nodes, Wq, Wk, Wv, Wo, x16, wcat, wo16);
    hipLaunchKernelGGL(gemm_qkv, dim3(64, 12), dim3(256), 0, stream,
                       x16, wcat, bq, bk, bv, q16, k16, v16);
    hipLaunchKernelGGL(attn_fused, dim3(64, 8), dim3(256), 0, stream,
                       q16, k16, v16, edges, rel_bias, attn16);
    hipLaunchKernelGGL(gemm_out, dim3(128, 4), dim3(256), 0, stream,
                       attn16, wo16, bo, out);
}